// Round 2
// baseline (2382.631 us; speedup 1.0000x reference)
//
#include <hip/hip_runtime.h>
#include <hip/hip_bf16.h>
#include <stdint.h>

// SparseMPNNLayer: bipartite MPNN, H=64. Round 2: dtype-adaptive (f32 vs bf16
// storage detected on-device), reduced ws footprint (26.4 MB).
//  phase1: edge MLP(concat(h_v[src], h_u[dst], e_feat)) 192->128->64 -> scatter-add m_u[dst]
//  phase2: node MLP(concat(h_u, m_u/S)) 128->64->64 -> h_u_out (written to d_out)
//  phase3: edge MLP(concat(h_u_out[dst], h_v[src], e_feat)) -> scatter-add m_v[src]
//  phase4: node MLP(concat(h_v, m_v/max(deg,1))) -> h_v_out
// Every compute kernel is templated on DT (0=f32 storage, 1=bf16 storage) and
// launched for both; a device flag (from detect_kernel) kills the wrong one.

__device__ __forceinline__ void unpack2(unsigned int u, float& a, float& b) {
    union { unsigned int i; float f; } x, y;
    x.i = u << 16;          // low half = element 0
    y.i = u & 0xffff0000u;  // high half = element 1
    a = x.f; b = y.f;
}

__device__ __forceinline__ void load16bf(const __hip_bfloat16* __restrict__ p, float* xr) {
    const uint4* q = reinterpret_cast<const uint4*>(p);
    uint4 a = q[0];
    uint4 b = q[1];
    unpack2(a.x, xr[0], xr[1]);  unpack2(a.y, xr[2], xr[3]);
    unpack2(a.z, xr[4], xr[5]);  unpack2(a.w, xr[6], xr[7]);
    unpack2(b.x, xr[8], xr[9]);  unpack2(b.y, xr[10], xr[11]);
    unpack2(b.z, xr[12], xr[13]); unpack2(b.w, xr[14], xr[15]);
}

__device__ __forceinline__ void load16f(const float* __restrict__ p, float* xr) {
    const float4* q = reinterpret_cast<const float4*>(p);
#pragma unroll
    for (int i = 0; i < 4; ++i) {
        float4 v = q[i];
        xr[4*i+0] = v.x; xr[4*i+1] = v.y; xr[4*i+2] = v.z; xr[4*i+3] = v.w;
    }
}

template <int DT>
__device__ __forceinline__ void load16seg(const void* base, size_t off, float* xr) {
    if (DT == 1) load16bf((const __hip_bfloat16*)base + off, xr);
    else         load16f((const float*)base + off, xr);
}

// Classify storage of h_v: packed-bf16 pairs have a bf16 exponent field in the
// low 16 bits of each u32 (~99.7% in [100,140] for N(0,1)); f32 mantissa bits
// hit that window ~16% of the time.
__global__ void detect_kernel(const unsigned int* __restrict__ hv, int* __restrict__ flag) {
    __shared__ int cnt;
    if (threadIdx.x == 0) cnt = 0;
    __syncthreads();
    unsigned int w = hv[threadIdx.x];
    int ef = (w >> 7) & 0xff;
    if (ef >= 100 && ef <= 140) atomicAdd(&cnt, 1);
    __syncthreads();
    if (threadIdx.x == 0) flag[0] = (cnt > 256) ? 1 : 0;
}

struct WArgs {
    const void* p[16];
    int off[16];
    int cnt[16];
};

template <int DT>
__global__ void cvt_all(WArgs wa, float* __restrict__ wf, const int* __restrict__ gflag) {
    if (gflag[0] != DT) return;
    const int t = blockIdx.y;
    const int i = blockIdx.x * 256 + threadIdx.x;
    if (i >= wa.cnt[t]) return;
    if (DT == 1) wf[wa.off[t] + i] = __bfloat162float(((const __hip_bfloat16*)wa.p[t])[i]);
    else         wf[wa.off[t] + i] = ((const float*)wa.p[t])[i];
}

__global__ void deg_kernel(const int* __restrict__ src, float* __restrict__ degv, int E) {
    int e = blockIdx.x * 256 + threadIdx.x;
    if (e < E) atomicAdd(&degv[src[e]], 1.0f);
}

// Edge MLP: K=192 -> 128 (relu) -> 64, scatter-add into accum rows.
// PHASE 1: x = [A=h_v[src] | B=h_u[dst] | e_feat], scatter row = dst
// PHASE 3: x = [A=h_u_out[dst] | B=h_v[src] | e_feat], scatter row = src
template <int DT, int PHASE>
__global__ __launch_bounds__(64)
void edge_mlp(const void* __restrict__ A, const void* __restrict__ B,
              const void* __restrict__ Efeat,
              const int* __restrict__ src_idx, const int* __restrict__ dst_idx,
              const int* __restrict__ gflag,
              const float* __restrict__ w1, const float* __restrict__ b1,
              const float* __restrict__ w2, const float* __restrict__ b2,
              float* __restrict__ accum, int E) {
    if (gflag[0] != DT) return;
    __shared__ float sm[64][65];
    __shared__ int rowS[64];

    const int lane = threadIdx.x;
    const int base = blockIdx.x * 64;
    const int cnt = min(64, E - base);
    const int eSafe = base + ((lane < cnt) ? lane : 0);
    const int s = src_idx[eSafe];
    const int d = dst_idx[eSafe];
    rowS[lane] = (PHASE == 1) ? d : s;

    const size_t offA = (size_t)((PHASE == 1) ? s : d) * 64;
    const size_t offB = (size_t)((PHASE == 1) ? d : s) * 64;
    const size_t offE = (size_t)eSafe * 64;

    float acc[64];
#pragma unroll
    for (int o = 0; o < 64; ++o) acc[o] = b2[o];

    for (int jc = 0; jc < 8; ++jc) {            // hidden 128 = 8 x 16
        float h[16];
#pragma unroll
        for (int j = 0; j < 16; ++j) h[j] = b1[jc * 16 + j];
        for (int kc = 0; kc < 12; ++kc) {       // K 192 = 12 x 16
            float xr[16];
            if (kc < 4)      load16seg<DT>(A, offA + kc * 16, xr);
            else if (kc < 8) load16seg<DT>(B, offB + (kc - 4) * 16, xr);
            else             load16seg<DT>(Efeat, offE + (kc - 8) * 16, xr);
#pragma unroll
            for (int k = 0; k < 16; ++k)
#pragma unroll
                for (int j = 0; j < 16; ++j)
                    h[j] = fmaf(xr[k], w1[(kc * 16 + k) * 128 + jc * 16 + j], h[j]);
        }
#pragma unroll
        for (int j = 0; j < 16; ++j) h[j] = fmaxf(h[j], 0.0f);
#pragma unroll
        for (int j = 0; j < 16; ++j)
#pragma unroll
            for (int o = 0; o < 64; ++o)
                acc[o] = fmaf(h[j], w2[(jc * 16 + j) * 64 + o], acc[o]);
    }

    // Transpose through LDS -> coalesced wave-wide atomic rows.
#pragma unroll
    for (int o = 0; o < 64; ++o) sm[lane][o] = acc[o];
    __syncthreads();
    for (int i = 0; i < cnt; ++i) {
        const int r = rowS[i];
        atomicAdd(&accum[(size_t)r * 64 + lane], sm[i][lane]);
    }
}

// Node MLP: K=128 -> 64 (relu) -> 64.
// PHASE 2: x = [h_u | m_u/S] -> out (h_u_out region of d_out)
// PHASE 4: x = [h_v | m_v/max(deg,1)] -> out (h_v_out region of d_out)
template <int DT, int PHASE>
__global__ __launch_bounds__(256)
void node_mlp(const void* __restrict__ hin,
              const float* __restrict__ m,
              const float* __restrict__ degv,
              const int* __restrict__ Sptr,
              const int* __restrict__ gflag,
              const float* __restrict__ w1, const float* __restrict__ b1,
              const float* __restrict__ w2, const float* __restrict__ b2,
              void* __restrict__ out,
              int N) {
    if (gflag[0] != DT) return;
    const int n = blockIdx.x * 256 + threadIdx.x;
    if (n >= N) return;
    const float scale = (PHASE == 2) ? (1.0f / (float)Sptr[0])
                                     : (1.0f / fmaxf(degv[n], 1.0f));
    const size_t offH = (size_t)n * 64;
    const float* pm = m + offH;

    float acc[64];
#pragma unroll
    for (int o = 0; o < 64; ++o) acc[o] = b2[o];

    for (int jc = 0; jc < 4; ++jc) {            // hidden 64 = 4 x 16
        float h[16];
#pragma unroll
        for (int j = 0; j < 16; ++j) h[j] = b1[jc * 16 + j];
        for (int kc = 0; kc < 8; ++kc) {        // K 128 = 8 x 16
            float xr[16];
            if (kc < 4) {
                load16seg<DT>(hin, offH + kc * 16, xr);
            } else {
                load16f(pm + (kc - 4) * 16, xr);
#pragma unroll
                for (int k = 0; k < 16; ++k) xr[k] *= scale;
            }
#pragma unroll
            for (int k = 0; k < 16; ++k)
#pragma unroll
                for (int j = 0; j < 16; ++j)
                    h[j] = fmaf(xr[k], w1[(kc * 16 + k) * 64 + jc * 16 + j], h[j]);
        }
#pragma unroll
        for (int j = 0; j < 16; ++j) h[j] = fmaxf(h[j], 0.0f);
#pragma unroll
        for (int j = 0; j < 16; ++j)
#pragma unroll
            for (int o = 0; o < 64; ++o)
                acc[o] = fmaf(h[j], w2[(jc * 16 + j) * 64 + o], acc[o]);
    }

    if (DT == 1) {
        unsigned int ob[32];
#pragma unroll
        for (int i = 0; i < 32; ++i) {
            __hip_bfloat162 p2 = __float22bfloat162_rn(make_float2(acc[2 * i], acc[2 * i + 1]));
            ob[i] = *reinterpret_cast<unsigned int*>(&p2);
        }
        uint4* qo = reinterpret_cast<uint4*>((__hip_bfloat16*)out + offH);
#pragma unroll
        for (int i = 0; i < 8; ++i) qo[i] = make_uint4(ob[4*i], ob[4*i+1], ob[4*i+2], ob[4*i+3]);
    } else {
        float4* qf = reinterpret_cast<float4*>((float*)out + offH);
#pragma unroll
        for (int i = 0; i < 16; ++i) qf[i] = make_float4(acc[4*i], acc[4*i+1], acc[4*i+2], acc[4*i+3]);
    }
}

extern "C" void kernel_launch(void* const* d_in, const int* in_sizes, int n_in,
                              void* d_out, int out_size, void* d_ws, size_t ws_size,
                              hipStream_t stream) {
    const void* h_v    = d_in[0];
    const void* h_u    = d_in[1];
    const void* e_feat = d_in[2];
    const int* eidx = (const int*)d_in[3];
    const int* Sptr = (const int*)d_in[4];

    const int NV_ = in_sizes[0] / 64;
    const int NU_ = in_sizes[1] / 64;
    const int E_  = in_sizes[2] / 64;
    const int* src = eidx;        // edge_index row 0 (indexes h_v)
    const int* dst = eidx + E_;   // edge_index row 1 (indexes h_u)

    const int maxN = (NV_ > NU_) ? NV_ : NU_;
    // ws layout: flag (64B) | mbuf[maxN*64] f32 | degv[NV] f32 | wf (f32 weights)
    int*   flag = (int*)d_ws;
    float* mbuf = (float*)((char*)d_ws + 64);
    float* degv = mbuf + (size_t)maxN * 64;
    float* wf   = degv + NV_;

    WArgs wa;
    int accum = 0;
    int maxCnt = 0;
    for (int i = 0; i < 16; ++i) {
        wa.p[i] = d_in[5 + i];
        wa.off[i] = accum;
        wa.cnt[i] = in_sizes[5 + i];
        accum += in_sizes[5 + i];
        if (in_sizes[5 + i] > maxCnt) maxCnt = in_sizes[5 + i];
    }

    detect_kernel<<<1, 512, 0, stream>>>((const unsigned int*)h_v, flag);

    dim3 cg((maxCnt + 255) / 256, 16);
    cvt_all<0><<<cg, 256, 0, stream>>>(wa, wf, flag);
    cvt_all<1><<<cg, 256, 0, stream>>>(wa, wf, flag);

    // Output regions per dtype interpretation.
    void* out_hv_f = d_out;
    void* out_hu_f = (void*)((float*)d_out + (size_t)NV_ * 64);
    void* out_hv_b = d_out;
    void* out_hu_b = (void*)((__hip_bfloat16*)d_out + (size_t)NV_ * 64);

    hipMemsetAsync(mbuf, 0, (size_t)maxN * 64 * sizeof(float), stream);

    const int egrid = (E_ + 63) / 64;
    edge_mlp<0, 1><<<egrid, 64, 0, stream>>>(h_v, h_u, e_feat, src, dst, flag,
        wf + wa.off[0], wf + wa.off[1], wf + wa.off[2], wf + wa.off[3], mbuf, E_);
    edge_mlp<1, 1><<<egrid, 64, 0, stream>>>(h_v, h_u, e_feat, src, dst, flag,
        wf + wa.off[0], wf + wa.off[1], wf + wa.off[2], wf + wa.off[3], mbuf, E_);

    const int ngridU = (NU_ + 255) / 256;
    node_mlp<0, 2><<<ngridU, 256, 0, stream>>>(h_u, mbuf, nullptr, Sptr, flag,
        wf + wa.off[4], wf + wa.off[5], wf + wa.off[6], wf + wa.off[7], out_hu_f, NU_);
    node_mlp<1, 2><<<ngridU, 256, 0, stream>>>(h_u, mbuf, nullptr, Sptr, flag,
        wf + wa.off[4], wf + wa.off[5], wf + wa.off[6], wf + wa.off[7], out_hu_b, NU_);

    hipMemsetAsync(mbuf, 0, (size_t)maxN * 64 * sizeof(float), stream);
    hipMemsetAsync(degv, 0, (size_t)NV_ * sizeof(float), stream);

    deg_kernel<<<(E_ + 255) / 256, 256, 0, stream>>>(src, degv, E_);

    edge_mlp<0, 3><<<egrid, 64, 0, stream>>>(out_hu_f, h_v, e_feat, src, dst, flag,
        wf + wa.off[8], wf + wa.off[9], wf + wa.off[10], wf + wa.off[11], mbuf, E_);
    edge_mlp<1, 3><<<egrid, 64, 0, stream>>>(out_hu_b, h_v, e_feat, src, dst, flag,
        wf + wa.off[8], wf + wa.off[9], wf + wa.off[10], wf + wa.off[11], mbuf, E_);

    const int ngridV = (NV_ + 255) / 256;
    node_mlp<0, 4><<<ngridV, 256, 0, stream>>>(h_v, mbuf, degv, Sptr, flag,
        wf + wa.off[12], wf + wa.off[13], wf + wa.off[14], wf + wa.off[15], out_hv_f, NV_);
    node_mlp<1, 4><<<ngridV, 256, 0, stream>>>(h_v, mbuf, degv, Sptr, flag,
        wf + wa.off[12], wf + wa.off[13], wf + wa.off[14], wf + wa.off[15], out_hv_b, NV_);
}